// Round 5
// baseline (19.119 us; speedup 1.0000x reference)
//
#include <hip/hip_runtime.h>

namespace {

constexpr int H = 256;
constexpr int Wd = 256;
constexpr int TW = 32;   // tile width  (pixels)
constexpr int TH = 16;   // tile height (pixels)
constexpr float EPS9 = 1e-7f / 9.0f;
constexpr float NINTH = 1.0f / 9.0f;
// s_img row pitch: 36 px * 8 ch + 4 pad -> rows shift bank sets by 4,
// 16B alignment preserved for float4 accesses.
constexpr int IPITCH = 36 * 8 + 4;   // 292 floats

// One block = one 32x16 pixel tile; each thread owns a horizontal PIXEL PAIR
// (2tx, 2tx+1) so center-stat records (40B, shared by adjacent pixels) and
// band-J reads are fetched once per pair instead of once per pixel:
// stats 18->12 records/thread-pair, J 26->16 reads. LDS traffic -32%.
// Algebra (validated R3/R4): diagonal cancels (window-mean identity), W
// symmetric -> 13 bands, weight 2 off-center. No global atomic: per-block
// partial to ws[bid]; kernel 2 reduces.
__global__ __launch_bounds__(256, 2)
void matting_loss_kernel(const float* __restrict__ content,
                         const float* __restrict__ stylized,
                         float* __restrict__ ws)
{
    const int b  = blockIdx.z;
    const int x0 = blockIdx.x * TW;
    const int y0 = blockIdx.y * TH;
    const int tid = threadIdx.x;
    const int tx = tid & 15;   // pair index: pixels 2tx, 2tx+1
    const int ty = tid >> 4;   // 0..15

    __shared__ __align__(16) float s_img[20 * IPITCH];     // [y][x*8 + m*4 + c]
    __shared__ __align__(16) float s_muk[2][18][34][4];    // mu0..2, scale
    __shared__ __align__(16) float s_A[2][18][34][6];      // a00,a01,a02,a11,a12,a22
    __shared__ float s_red[4];

    const size_t bofs = (size_t)b * 3 * H * Wd;
    const float* img0 = content + bofs;
    const float* img1 = stylized + bofs;

    // ---- Phase 1: stage 36x20 image tile (+2 halo), clamped ----
    for (int p = tid; p < 720; p += 256) {
        const int py = p / 36, px = p - py * 36;
        const int gy = min(max(y0 - 2 + py, 0), H - 1);
        const int gx = min(max(x0 - 2 + px, 0), Wd - 1);
        const int gi = gy * Wd + gx;
        float4 v0, v1;
        v0.x = img0[gi]; v0.y = img0[H * Wd + gi]; v0.z = img0[2 * H * Wd + gi]; v0.w = 0.f;
        v1.x = img1[gi]; v1.y = img1[H * Wd + gi]; v1.z = img1[2 * H * Wd + gi]; v1.w = 0.f;
        float* dst = &s_img[py * IPITCH + px * 8];
        *reinterpret_cast<float4*>(dst)     = v0;
        *reinterpret_cast<float4*>(dst + 4) = v1;
    }
    __syncthreads();

    // ---- Phase 2: per-center stats, 18x34 = 612 records x 2 images ----
    for (int p = tid; p < 612; p += 256) {
        const int cy = p / 34, cx = p - cy * 34;
        const int gy = y0 + cy - 1, gx = x0 + cx - 1;
        const bool valid = (gy >= 1) && (gy <= H - 2) && (gx >= 1) && (gx <= Wd - 2);
        const float scale = valid ? NINTH : 0.0f;
        #pragma unroll
        for (int m = 0; m < 2; ++m) {
            float s0=0.f,s1=0.f,s2=0.f,q00=0.f,q01=0.f,q02=0.f,q11=0.f,q12=0.f,q22=0.f;
            #pragma unroll
            for (int wy = 0; wy < 3; ++wy)
                #pragma unroll
                for (int wx = 0; wx < 3; ++wx) {
                    const float4 v = *reinterpret_cast<const float4*>(
                        &s_img[(cy + wy) * IPITCH + (cx + wx) * 8 + m * 4]);
                    s0 += v.x; s1 += v.y; s2 += v.z;
                    q00 += v.x * v.x; q01 += v.x * v.y; q02 += v.x * v.z;
                    q11 += v.y * v.y; q12 += v.y * v.z; q22 += v.z * v.z;
                }
            const float mu0 = s0 * NINTH, mu1 = s1 * NINTH, mu2 = s2 * NINTH;
            const float c00 = q00 * NINTH - mu0 * mu0 + EPS9;
            const float c01 = q01 * NINTH - mu0 * mu1;
            const float c02 = q02 * NINTH - mu0 * mu2;
            const float c11 = q11 * NINTH - mu1 * mu1 + EPS9;
            const float c12 = q12 * NINTH - mu1 * mu2;
            const float c22 = q22 * NINTH - mu2 * mu2 + EPS9;
            const float m00 = c11 * c22 - c12 * c12;
            const float m01 = c02 * c12 - c01 * c22;
            const float m02 = c01 * c12 - c02 * c11;
            const float det = c00 * m00 + c01 * m01 + c02 * m02;
            // invalid centers never divide; A=0 + scale=0 kills contribution.
            const float invdet = valid ? (1.0f / det) : 0.0f;
            float4 muk; muk.x = mu0; muk.y = mu1; muk.z = mu2; muk.w = scale;
            *reinterpret_cast<float4*>(&s_muk[m][cy][cx][0]) = muk;
            float* A = &s_A[m][cy][cx][0];
            float2 a0; a0.x = m00 * invdet;                  a0.y = m01 * invdet;
            float2 a1; a1.x = m02 * invdet;                  a1.y = (c00*c22 - c02*c02) * invdet;
            float2 a2; a2.x = (c01*c02 - c00*c12) * invdet;  a2.y = (c00*c11 - c01*c01) * invdet;
            reinterpret_cast<float2*>(A)[0] = a0;
            reinterpret_cast<float2*>(A)[1] = a1;
            reinterpret_cast<float2*>(A)[2] = a2;
        }
    }
    __syncthreads();

    // ---- Phase 3: pixel-pair t-records ----
    // Pair pixels pA=2tx, pB=2tx+1 (tile cols). Centers needed: rows ty..ty+2,
    // cols c0..c0+3 with c0=2tx; pA uses cols c0..c0+2 (ex=c), pB c0+1..c0+3
    // (ex=c-1). Each record read ONCE, used by both pixels.
    const int c0 = 2 * tx;
    float stA[2][3][3][3];   // [img][ey][ex][ch]
    float stB[2][3][3][3];
    float ckdA[3][3], ckdB[3][3];

    const float* IiP = &s_img[(ty + 2) * IPITCH + (c0 + 2) * 8];
    const float4 IA0 = *reinterpret_cast<const float4*>(IiP);
    const float4 IA1 = *reinterpret_cast<const float4*>(IiP + 4);
    const float4 IB0 = *reinterpret_cast<const float4*>(IiP + 8);
    const float4 IB1 = *reinterpret_cast<const float4*>(IiP + 12);

    #pragma unroll
    for (int ey = 0; ey < 3; ++ey)
    #pragma unroll
    for (int c = 0; c < 4; ++c) {
        const int cy = ty + ey, cx = c0 + c;
        float kA[2], kB[2];
        #pragma unroll
        for (int m = 0; m < 2; ++m) {
            const float4 muk = *reinterpret_cast<const float4*>(&s_muk[m][cy][cx][0]);
            const float* Ap = &s_A[m][cy][cx][0];
            const float2 a0 = reinterpret_cast<const float2*>(Ap)[0];  // a00,a01
            const float2 a1 = reinterpret_cast<const float2*>(Ap)[1];  // a02,a11
            const float2 a2 = reinterpret_cast<const float2*>(Ap)[2];  // a12,a22
            const float s = muk.w;
            if (c < 3) {   // pixel A, rel col ex=c
                const float4 Ii = (m == 0) ? IA0 : IA1;
                const float u0 = Ii.x - muk.x, u1 = Ii.y - muk.y, u2 = Ii.z - muk.z;
                const float t0 = a0.x*u0 + a0.y*u1 + a1.x*u2;
                const float t1 = a0.y*u0 + a1.y*u1 + a2.x*u2;
                const float t2 = a1.x*u0 + a2.x*u1 + a2.y*u2;
                stA[m][ey][c][0] = s*t0; stA[m][ey][c][1] = s*t1; stA[m][ey][c][2] = s*t2;
                kA[m] = s * (1.0f - (t0*muk.x + t1*muk.y + t2*muk.z));
            }
            if (c > 0) {   // pixel B, rel col ex=c-1
                const float4 Ii = (m == 0) ? IB0 : IB1;
                const float u0 = Ii.x - muk.x, u1 = Ii.y - muk.y, u2 = Ii.z - muk.z;
                const float t0 = a0.x*u0 + a0.y*u1 + a1.x*u2;
                const float t1 = a0.y*u0 + a1.y*u1 + a2.x*u2;
                const float t2 = a1.x*u0 + a2.x*u1 + a2.y*u2;
                stB[m][ey][c-1][0] = s*t0; stB[m][ey][c-1][1] = s*t1; stB[m][ey][c-1][2] = s*t2;
                kB[m] = s * (1.0f - (t0*muk.x + t1*muk.y + t2*muk.z));
            }
        }
        if (c < 3) ckdA[ey][c]   = kA[1] - kA[0];
        if (c > 0) ckdB[ey][c-1] = kB[1] - kB[0];
    }

    // ---- Band accumulation: 13 bands per pixel, shared J-row registers ----
    float loss2 = 0.f, loss1 = 0.f;

    // Per-pixel band body, fully static indexing (macro to avoid runtime
    // array-pointer selection -> scratch).
    #define BAND_BODY(ST, CKD, QOFF)                                              \
    {                                                                             \
        float Rk[3], R0[3][3], R1[3][3];                                          \
        _Pragma("unroll")                                                         \
        for (int ex = 0; ex < 3; ++ex) {                                          \
            float rk=0.f,r00=0.f,r01=0.f,r02=0.f,r10=0.f,r11=0.f,r12=0.f;         \
            _Pragma("unroll")                                                     \
            for (int ey = 0; ey < 3; ++ey) {                                      \
                if (ey >= by - 2) {                                               \
                    rk  += CKD[ey][ex];                                           \
                    r00 += ST[0][ey][ex][0]; r01 += ST[0][ey][ex][1];             \
                    r02 += ST[0][ey][ex][2];                                      \
                    r10 += ST[1][ey][ex][0]; r11 += ST[1][ey][ex][1];             \
                    r12 += ST[1][ey][ex][2];                                      \
                }                                                                 \
            }                                                                     \
            Rk[ex] = rk;                                                          \
            R0[ex][0] = r00; R0[ex][1] = r01; R0[ex][2] = r02;                    \
            R1[ex][0] = r10; R1[ex][1] = r11; R1[ex][2] = r12;                    \
        }                                                                         \
        _Pragma("unroll")                                                         \
        for (int bx = 0; bx < 5; ++bx) {                                          \
            if (by == 2 && bx < 2) continue;                                      \
            float Tk=0.f,T00=0.f,T01=0.f,T02=0.f,T10=0.f,T11=0.f,T12=0.f;         \
            _Pragma("unroll")                                                     \
            for (int ex = 0; ex < 3; ++ex) {                                      \
                if (ex >= bx - 2 && ex <= bx) {                                   \
                    Tk  += Rk[ex];                                                \
                    T00 += R0[ex][0]; T01 += R0[ex][1]; T02 += R0[ex][2];         \
                    T10 += R1[ex][0]; T11 += R1[ex][1]; T12 += R1[ex][2];         \
                }                                                                 \
            }                                                                     \
            const float4 Jv0 = J0r[bx + QOFF];                                    \
            const float4 Jv1 = J1r[bx + QOFF];                                    \
            const float dd = Tk + (T10*Jv1.x + T11*Jv1.y + T12*Jv1.z)             \
                                - (T00*Jv0.x + T01*Jv0.y + T02*Jv0.z);            \
            if (by == 2 && bx == 2) loss1 += dd * dd;                             \
            else                    loss2 += dd * dd;                             \
        }                                                                         \
    }

    #pragma unroll
    for (int by = 2; by <= 4; ++by) {
        // J-row registers: cols c0+q, q in [qlo..5] (by==2 only needs q>=2)
        float4 J0r[6], J1r[6];
        const float* jrow = &s_img[(ty + by) * IPITCH + c0 * 8];
        #pragma unroll
        for (int q = 0; q < 6; ++q) {
            if (by == 2 && q < 2) continue;
            J0r[q] = *reinterpret_cast<const float4*>(jrow + q * 8);
            J1r[q] = *reinterpret_cast<const float4*>(jrow + q * 8 + 4);
        }
        BAND_BODY(stA, ckdA, 0)   // pixel A: J col = c0 + bx
        BAND_BODY(stB, ckdB, 1)   // pixel B: J col = c0 + bx + 1
    }
    #undef BAND_BODY

    float loss = 2.0f * loss2 + loss1;

    // ---- Phase 4: block reduce, one plain store per block ----
    #pragma unroll
    for (int off = 32; off >= 1; off >>= 1)
        loss += __shfl_down(loss, off, 64);
    if ((tid & 63) == 0) s_red[tid >> 6] = loss;
    __syncthreads();
    if (tid == 0) {
        const int bid = (blockIdx.z * gridDim.y + blockIdx.y) * gridDim.x + blockIdx.x;
        ws[bid] = s_red[0] + s_red[1] + s_red[2] + s_red[3];
    }
}

// Kernel 2: deterministic reduction of per-block partials.
__global__ __launch_bounds__(256)
void reduce_kernel(const float* __restrict__ ws, float* __restrict__ out,
                   int n, float inv_denom)
{
    __shared__ float s_red[4];
    const int tid = threadIdx.x;
    float acc = 0.f;
    for (int i = tid; i < n; i += 256) acc += ws[i];
    #pragma unroll
    for (int off = 32; off >= 1; off >>= 1)
        acc += __shfl_down(acc, off, 64);
    if ((tid & 63) == 0) s_red[tid >> 6] = acc;
    __syncthreads();
    if (tid == 0)
        out[0] = (s_red[0] + s_red[1] + s_red[2] + s_red[3]) * inv_denom;
}

} // namespace

extern "C" void kernel_launch(void* const* d_in, const int* in_sizes, int n_in,
                              void* d_out, int out_size, void* d_ws, size_t ws_size,
                              hipStream_t stream) {
    const float* content  = (const float*)d_in[0];
    const float* stylized = (const float*)d_in[1];
    float* out = (float*)d_out;
    float* ws  = (float*)d_ws;

    const int B = in_sizes[0] / (3 * H * Wd);
    const float inv_denom =
        1.0f / ((float)B * (float)(H * Wd) * (float)(H * Wd));

    dim3 grid(Wd / TW, H / TH, B);
    const int nblocks = grid.x * grid.y * grid.z;
    matting_loss_kernel<<<grid, 256, 0, stream>>>(content, stylized, ws);
    reduce_kernel<<<1, 256, 0, stream>>>(ws, out, nblocks, inv_denom);
}

// Round 6
// 18.803 us; speedup vs baseline: 1.0168x; 1.0168x over previous
//
#include <hip/hip_runtime.h>

namespace {

constexpr int H = 256;
constexpr int Wd = 256;
constexpr int TILE = 16;
constexpr float EPS9 = 1e-7f / 9.0f;
constexpr float NINTH = 1.0f / 9.0f;
// s_img row pitch: 20 px * 8 ch + 4 pad -> consecutive rows shift bank sets
// by 4 while keeping 16B alignment for float4 accesses.
constexpr int IPITCH = 164;

// One block = one 16x16 pixel tile of one batch image pair (R4 structure —
// 39 KB LDS => 4 blocks/CU resident with launch_bounds(256,4)).
// Algebra (validated R3/R4): Laplacian diagonal cancels (window-mean
// identity), W symmetric -> 13 bands, weight 2 off-center.
// Phase 3 processes images SEQUENTIALLY, accumulating signed dd[band]:
// identical LDS traffic to R4, but ~95 live floats -> fits 128-VGPR cap
// -> 16 waves/CU for latency hiding (R4/R5 evidence: latency-bound, not
// throughput-bound). No global atomic: partial to ws[bid]; kernel 2 reduces.
__global__ __launch_bounds__(256, 4)
void matting_loss_kernel(const float* __restrict__ content,
                         const float* __restrict__ stylized,
                         float* __restrict__ ws)
{
    const int b  = blockIdx.z;
    const int x0 = blockIdx.x * TILE;
    const int y0 = blockIdx.y * TILE;
    const int tid = threadIdx.x;
    const int tx = tid & (TILE - 1);
    const int ty = tid >> 4;

    __shared__ __align__(16) float s_img[20 * IPITCH];     // [y][x*8 + m*4 + c]
    __shared__ __align__(16) float s_muk[2][18][18][4];    // mu0..2, scale
    __shared__ __align__(16) float s_A[2][18][18][6];      // a00,a01,a02,a11,a12,a22
    __shared__ float s_red[4];

    const size_t bofs = (size_t)b * 3 * H * Wd;
    const float* img0 = content + bofs;
    const float* img1 = stylized + bofs;

    // ---- Phase 1: stage 20x20 image tile (+2 halo), clamped ----
    for (int p = tid; p < 400; p += 256) {
        const int py = p / 20, px = p - py * 20;
        const int gy = min(max(y0 - 2 + py, 0), H - 1);
        const int gx = min(max(x0 - 2 + px, 0), Wd - 1);
        const int gi = gy * Wd + gx;
        float4 v0, v1;
        v0.x = img0[gi]; v0.y = img0[H * Wd + gi]; v0.z = img0[2 * H * Wd + gi]; v0.w = 0.f;
        v1.x = img1[gi]; v1.y = img1[H * Wd + gi]; v1.z = img1[2 * H * Wd + gi]; v1.w = 0.f;
        float* dst = &s_img[py * IPITCH + px * 8];
        *reinterpret_cast<float4*>(dst)     = v0;
        *reinterpret_cast<float4*>(dst + 4) = v1;
    }
    __syncthreads();

    // ---- Phase 2: per-center stats (mean + inverse covariance) ----
    for (int p = tid; p < 324; p += 256) {
        const int cy = p / 18, cx = p - cy * 18;
        const int gy = y0 - 1 + cy, gx = x0 - 1 + cx;
        const bool valid = (gy >= 1) && (gy <= H - 2) && (gx >= 1) && (gx <= Wd - 2);
        const float scale = valid ? NINTH : 0.0f;
        #pragma unroll
        for (int m = 0; m < 2; ++m) {
            float s0=0.f,s1=0.f,s2=0.f,q00=0.f,q01=0.f,q02=0.f,q11=0.f,q12=0.f,q22=0.f;
            #pragma unroll
            for (int wy = 0; wy < 3; ++wy)
                #pragma unroll
                for (int wx = 0; wx < 3; ++wx) {
                    const float4 v = *reinterpret_cast<const float4*>(
                        &s_img[(cy + wy) * IPITCH + (cx + wx) * 8 + m * 4]);
                    s0 += v.x; s1 += v.y; s2 += v.z;
                    q00 += v.x * v.x; q01 += v.x * v.y; q02 += v.x * v.z;
                    q11 += v.y * v.y; q12 += v.y * v.z; q22 += v.z * v.z;
                }
            const float mu0 = s0 * NINTH, mu1 = s1 * NINTH, mu2 = s2 * NINTH;
            const float c00 = q00 * NINTH - mu0 * mu0 + EPS9;
            const float c01 = q01 * NINTH - mu0 * mu1;
            const float c02 = q02 * NINTH - mu0 * mu2;
            const float c11 = q11 * NINTH - mu1 * mu1 + EPS9;
            const float c12 = q12 * NINTH - mu1 * mu2;
            const float c22 = q22 * NINTH - mu2 * mu2 + EPS9;
            const float m00 = c11 * c22 - c12 * c12;
            const float m01 = c02 * c12 - c01 * c22;
            const float m02 = c01 * c12 - c02 * c11;
            const float det = c00 * m00 + c01 * m01 + c02 * m02;
            // invalid centers never divide; A=0 + scale=0 kills contribution.
            const float invdet = valid ? (1.0f / det) : 0.0f;
            float4 muk; muk.x = mu0; muk.y = mu1; muk.z = mu2; muk.w = scale;
            *reinterpret_cast<float4*>(&s_muk[m][cy][cx][0]) = muk;
            float* A = &s_A[m][cy][cx][0];
            float2 a0; a0.x = m00 * invdet;                  a0.y = m01 * invdet;
            float2 a1; a1.x = m02 * invdet;                  a1.y = (c00*c22 - c02*c02) * invdet;
            float2 a2; a2.x = (c01*c02 - c00*c12) * invdet;  a2.y = (c00*c11 - c01*c01) * invdet;
            reinterpret_cast<float2*>(A)[0] = a0;
            reinterpret_cast<float2*>(A)[1] = a1;
            reinterpret_cast<float2*>(A)[2] = a2;
        }
    }
    __syncthreads();

    // ---- Phase 3: sequential-image band accumulation ----
    // dd[band] = (k1 + T1.J1) - (k0 + T0.J0); per image: records
    //   t = A (I_i - mu), st = s*t, ck = s*(1 - t.mu), K/T prefix-summed
    //   over the centers serving each band. Band idx = (by-2)*5 + bx - 2.
    float dd[13];
    #pragma unroll
    for (int q = 0; q < 13; ++q) dd[q] = 0.f;

    #pragma unroll
    for (int m = 0; m < 2; ++m) {
        const float sign = (m == 0) ? -1.0f : 1.0f;
        const float4 Ii = *reinterpret_cast<const float4*>(
            &s_img[(ty + 2) * IPITCH + (tx + 2) * 8 + m * 4]);

        float st[3][3][3];   // [ey][ex][ch]
        float ck[3][3];
        #pragma unroll
        for (int ey = 0; ey < 3; ++ey)
        #pragma unroll
        for (int ex = 0; ex < 3; ++ex) {
            const float4 muk = *reinterpret_cast<const float4*>(&s_muk[m][ty + ey][tx + ex][0]);
            const float* Ap = &s_A[m][ty + ey][tx + ex][0];
            const float2 a0 = reinterpret_cast<const float2*>(Ap)[0];  // a00,a01
            const float2 a1 = reinterpret_cast<const float2*>(Ap)[1];  // a02,a11
            const float2 a2 = reinterpret_cast<const float2*>(Ap)[2];  // a12,a22
            const float u0 = Ii.x - muk.x, u1 = Ii.y - muk.y, u2 = Ii.z - muk.z;
            const float t0 = a0.x*u0 + a0.y*u1 + a1.x*u2;
            const float t1 = a0.y*u0 + a1.y*u1 + a2.x*u2;
            const float t2 = a1.x*u0 + a2.x*u1 + a2.y*u2;
            const float s = muk.w;
            st[ey][ex][0] = s*t0; st[ey][ex][1] = s*t1; st[ey][ex][2] = s*t2;
            ck[ey][ex] = s * (1.0f - (t0*muk.x + t1*muk.y + t2*muk.z));
        }

        #pragma unroll
        for (int by = 2; by <= 4; ++by) {
            // J-row registers for this image: cols tx+q, q in [qlo..4]
            float4 Jr[5];
            const float* jrow = &s_img[(ty + by) * IPITCH + tx * 8 + m * 4];
            #pragma unroll
            for (int q = 0; q < 5; ++q) {
                if (by == 2 && q < 2) continue;
                Jr[q] = *reinterpret_cast<const float4*>(jrow + q * 8);
            }
            // column partials over center rows ey in [by-2, 2]
            float Rk[3], R[3][3];
            #pragma unroll
            for (int ex = 0; ex < 3; ++ex) {
                float rk = 0.f, r0 = 0.f, r1 = 0.f, r2 = 0.f;
                #pragma unroll
                for (int ey = 0; ey < 3; ++ey) {
                    if (ey >= by - 2) {   // compile-time after unroll
                        rk += ck[ey][ex];
                        r0 += st[ey][ex][0]; r1 += st[ey][ex][1]; r2 += st[ey][ex][2];
                    }
                }
                Rk[ex] = rk; R[ex][0] = r0; R[ex][1] = r1; R[ex][2] = r2;
            }
            #pragma unroll
            for (int bx = 0; bx < 5; ++bx) {
                if (by == 2 && bx < 2) continue;   // only bands >= center
                float Tk = 0.f, T0 = 0.f, T1 = 0.f, T2 = 0.f;
                #pragma unroll
                for (int ex = 0; ex < 3; ++ex) {
                    if (ex >= bx - 2 && ex <= bx) {
                        Tk += Rk[ex];
                        T0 += R[ex][0]; T1 += R[ex][1]; T2 += R[ex][2];
                    }
                }
                const int idx = (by - 2) * 5 + bx - 2;   // compile-time const
                const float4 J = Jr[bx];
                dd[idx] += sign * (Tk + T0 * J.x + T1 * J.y + T2 * J.z);
            }
        }
    }

    float loss = dd[0] * dd[0];            // center band, weight 1
    float loss2 = 0.f;
    #pragma unroll
    for (int q = 1; q < 13; ++q) loss2 += dd[q] * dd[q];
    loss += 2.0f * loss2;                  // symmetry weight

    // ---- Phase 4: block reduce, one plain store per block ----
    #pragma unroll
    for (int off = 32; off >= 1; off >>= 1)
        loss += __shfl_down(loss, off, 64);
    if ((tid & 63) == 0) s_red[tid >> 6] = loss;
    __syncthreads();
    if (tid == 0) {
        const int bid = (blockIdx.z * gridDim.y + blockIdx.y) * gridDim.x + blockIdx.x;
        ws[bid] = s_red[0] + s_red[1] + s_red[2] + s_red[3];
    }
}

// Kernel 2: deterministic reduction of per-block partials.
__global__ __launch_bounds__(256)
void reduce_kernel(const float* __restrict__ ws, float* __restrict__ out,
                   int n, float inv_denom)
{
    __shared__ float s_red[4];
    const int tid = threadIdx.x;
    float acc = 0.f;
    for (int i = tid; i < n; i += 256) acc += ws[i];
    #pragma unroll
    for (int off = 32; off >= 1; off >>= 1)
        acc += __shfl_down(acc, off, 64);
    if ((tid & 63) == 0) s_red[tid >> 6] = acc;
    __syncthreads();
    if (tid == 0)
        out[0] = (s_red[0] + s_red[1] + s_red[2] + s_red[3]) * inv_denom;
}

} // namespace

extern "C" void kernel_launch(void* const* d_in, const int* in_sizes, int n_in,
                              void* d_out, int out_size, void* d_ws, size_t ws_size,
                              hipStream_t stream) {
    const float* content  = (const float*)d_in[0];
    const float* stylized = (const float*)d_in[1];
    float* out = (float*)d_out;
    float* ws  = (float*)d_ws;

    const int B = in_sizes[0] / (3 * H * Wd);
    const float inv_denom =
        1.0f / ((float)B * (float)(H * Wd) * (float)(H * Wd));

    dim3 grid(Wd / TILE, H / TILE, B);
    const int nblocks = grid.x * grid.y * grid.z;
    matting_loss_kernel<<<grid, 256, 0, stream>>>(content, stylized, ws);
    reduce_kernel<<<1, 256, 0, stream>>>(ws, out, nblocks, inv_denom);
}